// Round 2
// baseline (297.247 us; speedup 1.0000x reference)
//
#include <hip/hip_runtime.h>

// ---------------------------------------------------------------------------
// TransformerBlock: LN1 -> QKV -> attn(+bias, softmax) -> Wo(+x) -> LN2
//                   -> FFN1(+mish) -> FFN2(+residual)
// fp32 I/O, bf16 MFMA GEMMs (16x16x32), flash-style attention.
// ---------------------------------------------------------------------------

typedef __attribute__((ext_vector_type(8))) __bf16 bf16x8;
typedef __attribute__((ext_vector_type(4))) float  f32x4;

#define LOG2E 1.4426950408889634f

__device__ __forceinline__ unsigned short f2bf(float f) {
  unsigned int u = __builtin_bit_cast(unsigned int, f);
  u += 0x7fffu + ((u >> 16) & 1u);          // round-to-nearest-even
  return (unsigned short)(u >> 16);
}

// ---------------------------------------------------------------------------
// Weight convert fp32 (K x N) -> bf16 transposed (N x K), LDS 32x33 tile.
// ---------------------------------------------------------------------------
__global__ void convert_transpose(const float* __restrict__ W,
                                  unsigned short* __restrict__ Wt,
                                  int K, int N) {
  __shared__ float tile[32][33];
  const int n0 = blockIdx.x * 32, k0 = blockIdx.y * 32;
  const int tx = threadIdx.x, ty = threadIdx.y;   // (32,8)
#pragma unroll
  for (int r = 0; r < 4; ++r)
    tile[ty + 8 * r][tx] = W[(size_t)(k0 + ty + 8 * r) * N + n0 + tx];
  __syncthreads();
#pragma unroll
  for (int r = 0; r < 4; ++r)
    Wt[(size_t)(n0 + ty + 8 * r) * K + k0 + tx] = f2bf(tile[tx][ty + 8 * r]);
}

// ---------------------------------------------------------------------------
// LayerNorm over D=1024, one row per block (256 threads, 4 f32/thread),
// bf16 output.
// ---------------------------------------------------------------------------
__global__ __launch_bounds__(256) void ln_kernel(const float* __restrict__ in,
                                                 const float* __restrict__ g,
                                                 const float* __restrict__ b,
                                                 unsigned short* __restrict__ out) {
  const int row = blockIdx.x;
  const int t = threadIdx.x;
  const float4 v = reinterpret_cast<const float4*>(in + (size_t)row * 1024)[t];
  float s  = v.x + v.y + v.z + v.w;
  float s2 = v.x * v.x + v.y * v.y + v.z * v.z + v.w * v.w;
#pragma unroll
  for (int m = 1; m < 64; m <<= 1) { s += __shfl_xor(s, m); s2 += __shfl_xor(s2, m); }
  __shared__ float ps[4], ps2[4];
  const int wv = t >> 6;
  if ((t & 63) == 0) { ps[wv] = s; ps2[wv] = s2; }
  __syncthreads();
  float ts = 0.f, ts2 = 0.f;
#pragma unroll
  for (int i = 0; i < 4; ++i) { ts += ps[i]; ts2 += ps2[i]; }
  const float mu = ts * (1.f / 1024.f);
  const float var = ts2 * (1.f / 1024.f) - mu * mu;
  const float rstd = rsqrtf(var + 1e-5f);
  const float4 gg = reinterpret_cast<const float4*>(g)[t];
  const float4 bb = reinterpret_cast<const float4*>(b)[t];
  ushort4 ov;
  ov.x = f2bf((v.x - mu) * rstd * gg.x + bb.x);
  ov.y = f2bf((v.y - mu) * rstd * gg.y + bb.y);
  ov.z = f2bf((v.z - mu) * rstd * gg.z + bb.z);
  ov.w = f2bf((v.w - mu) * rstd * gg.w + bb.w);
  *reinterpret_cast<ushort4*>(out + (size_t)row * 1024 + t * 4) = ov;
}

// ---------------------------------------------------------------------------
// GEMM: C(MxN) = A(MxK bf16, row-major) @ Bt(NxK bf16, row-major)^T + bias
// 128x128 tile, BK=32, 4 waves (2x2), 16x16x32 MFMA, 4x4 frags/wave.
// MODE 0: QKV scatter -> q[b,h,s,d], k[b,h,s,d], vt[b,h,d,s] (bf16)
// MODE 1: r1 = acc + bo + x            (fp32)
// MODE 2: ffn1 = mish(acc + b1)        (bf16)
// MODE 3: out = acc + b2 + r1          (fp32)
// ---------------------------------------------------------------------------
template <int MODE>
__global__ __launch_bounds__(256, 2) void gemm_kernel(
    const unsigned short* __restrict__ A, const unsigned short* __restrict__ Bt,
    const float* __restrict__ bias, int M, int N, int K,
    float* __restrict__ outf, const float* __restrict__ res,
    unsigned short* __restrict__ outb,
    unsigned short* __restrict__ kbuf, unsigned short* __restrict__ vtbuf) {
  constexpr int BK = 32;
  constexpr int LDT = 40;                 // 80B row stride: 16B-aligned, ~2-way banks
  __shared__ unsigned short a_sh[128 * LDT];
  __shared__ unsigned short b_sh[128 * LDT];

  const int tid = threadIdx.x;
  const int wave = tid >> 6, lane = tid & 63;
  const int wm = wave >> 1, wn = wave & 1;
  const int l15 = lane & 15, l4 = lane >> 4;
  const long bm0 = (long)blockIdx.y * 128;
  const long bn0 = (long)blockIdx.x * 128;

  const int srow = tid >> 1;              // 2 threads per 128-row (BK=32 -> 64B)
  const int scol = (tid & 1) * 16;        // bf16 offset

  const unsigned short* aG = A + (bm0 + srow) * (long)K + scol;
  const unsigned short* bG = Bt + (bn0 + srow) * (long)K + scol;
  unsigned short* aS = &a_sh[srow * LDT + scol];
  unsigned short* bS = &b_sh[srow * LDT + scol];

  f32x4 acc[4][4] = {};

  for (int k0 = 0; k0 < K; k0 += BK) {
    const uint4 av0 = reinterpret_cast<const uint4*>(aG + k0)[0];
    const uint4 av1 = reinterpret_cast<const uint4*>(aG + k0)[1];
    const uint4 bv0 = reinterpret_cast<const uint4*>(bG + k0)[0];
    const uint4 bv1 = reinterpret_cast<const uint4*>(bG + k0)[1];
    __syncthreads();                       // previous tile fully consumed
    reinterpret_cast<uint4*>(aS)[0] = av0;
    reinterpret_cast<uint4*>(aS + 8)[0] = av1;
    reinterpret_cast<uint4*>(bS)[0] = bv0;
    reinterpret_cast<uint4*>(bS + 8)[0] = bv1;
    __syncthreads();

    bf16x8 af[4], bf[4];
#pragma unroll
    for (int mf = 0; mf < 4; ++mf)
      af[mf] = *reinterpret_cast<const bf16x8*>(&a_sh[(wm * 64 + mf * 16 + l15) * LDT + 8 * l4]);
#pragma unroll
    for (int nf = 0; nf < 4; ++nf)
      bf[nf] = *reinterpret_cast<const bf16x8*>(&b_sh[(wn * 64 + nf * 16 + l15) * LDT + 8 * l4]);
#pragma unroll
    for (int mf = 0; mf < 4; ++mf)
#pragma unroll
      for (int nf = 0; nf < 4; ++nf)
        acc[mf][nf] = __builtin_amdgcn_mfma_f32_16x16x32_bf16(af[mf], bf[nf], acc[mf][nf], 0, 0, 0);
  }

  // epilogue: C layout col = lane&15, row = 4*(lane>>4)+r  [m89/m91 verified]
#pragma unroll
  for (int mf = 0; mf < 4; ++mf) {
#pragma unroll
    for (int nf = 0; nf < 4; ++nf) {
#pragma unroll
      for (int r = 0; r < 4; ++r) {
        const long row = bm0 + wm * 64 + mf * 16 + 4 * l4 + r;
        const long col = bn0 + wn * 64 + nf * 16 + l15;
        float v = acc[mf][nf][r] + bias[col];
        if constexpr (MODE == 0) {
          const int n = (int)col;
          const int which = n >> 10, rem = n & 1023;
          const int head = rem >> 6, d = rem & 63;
          const int b = (int)(row >> 10), s = (int)(row & 1023);
          const unsigned short bv = f2bf(v);
          const long qi = ((long)(b * 16 + head) * 1024 + s) * 64 + d;
          if (which == 0)      outb[qi] = bv;
          else if (which == 1) kbuf[qi] = bv;
          else                 vtbuf[((long)(b * 16 + head) * 64 + d) * 1024 + s] = bv;
        } else if constexpr (MODE == 1) {
          outf[row * N + col] = v + res[row * N + col];
        } else if constexpr (MODE == 2) {
          const float sp = (v > 20.f) ? v : log1pf(expf(v));
          outb[row * (long)N + col] = f2bf(v * tanhf(sp));
        } else {
          outf[row * N + col] = v + res[row * N + col];
        }
      }
    }
  }
}

// ---------------------------------------------------------------------------
// Flash attention: grid (S/64, B*H), 256 threads (4 waves x 16 q-rows).
// K staged [kv][d], V staged pre-transposed [d][kv]; online softmax; P via LDS.
// scores = (q @ k^T) * 0.125 + bias ; ctx -> [b, s, h*64+d] bf16.
// ---------------------------------------------------------------------------
__global__ __launch_bounds__(256, 2) void attn_kernel(
    const unsigned short* __restrict__ qb, const unsigned short* __restrict__ kb,
    const unsigned short* __restrict__ vtb, const float* __restrict__ bias,
    unsigned short* __restrict__ ctx) {
  constexpr int S = 1024, LKV = 72;       // 144B row stride: 16B-aligned
  __shared__ unsigned short k_sh[64 * LKV];
  __shared__ unsigned short vt_sh[64 * LKV];
  __shared__ unsigned short p_sh[4][16 * LKV];

  const int bh = blockIdx.y;              // b*16 + h
  const int q0 = blockIdx.x * 64;
  const int tid = threadIdx.x, wave = tid >> 6, lane = tid & 63;
  const int l15 = lane & 15, l4 = lane >> 4;

  const long qbase = ((long)bh * S + q0 + wave * 16 + l15) * 64;
  const bf16x8 qf0 = *reinterpret_cast<const bf16x8*>(qb + qbase + 8 * l4);
  const bf16x8 qf1 = *reinterpret_cast<const bf16x8*>(qb + qbase + 8 * l4 + 32);

  // 64-row x 64-col (bf16) tiles: 4 threads per 128B row, 32B per thread
  const int srow = tid >> 2;              // 0..63
  const int scol = (tid & 3) * 16;        // shorts; this thread covers [scol, scol+16)

  f32x4 oacc[4] = {};
  float mrun[4], lsum[4] = {};
#pragma unroll
  for (int r = 0; r < 4; ++r) mrun[r] = -1e30f;

  const float* brow = bias + ((long)bh * S + q0 + wave * 16) * S;

  for (int kv0 = 0; kv0 < S; kv0 += 64) {
    const unsigned short* kG = kb + ((long)bh * S + kv0 + srow) * 64 + scol;
    const unsigned short* vG = vtb + ((long)bh * 64 + srow) * S + kv0 + scol;
    const uint4 k0v = reinterpret_cast<const uint4*>(kG)[0];
    const uint4 k1v = reinterpret_cast<const uint4*>(kG)[1];
    const uint4 v0v = reinterpret_cast<const uint4*>(vG)[0];
    const uint4 v1v = reinterpret_cast<const uint4*>(vG)[1];
    __syncthreads();
    reinterpret_cast<uint4*>(&k_sh[srow * LKV + scol])[0] = k0v;
    reinterpret_cast<uint4*>(&k_sh[srow * LKV + scol + 8])[0] = k1v;
    reinterpret_cast<uint4*>(&vt_sh[srow * LKV + scol])[0] = v0v;
    reinterpret_cast<uint4*>(&vt_sh[srow * LKV + scol + 8])[0] = v1v;
    __syncthreads();

    // QK^T: 16x64 scores per wave
    f32x4 sc[4];
#pragma unroll
    for (int nf = 0; nf < 4; ++nf) {
      const unsigned short* kr = &k_sh[(nf * 16 + l15) * LKV + 8 * l4];
      const bf16x8 kf0 = *reinterpret_cast<const bf16x8*>(kr);
      const bf16x8 kf1 = *reinterpret_cast<const bf16x8*>(kr + 32);
      f32x4 z = {};
      z = __builtin_amdgcn_mfma_f32_16x16x32_bf16(qf0, kf0, z, 0, 0, 0);
      sc[nf] = __builtin_amdgcn_mfma_f32_16x16x32_bf16(qf1, kf1, z, 0, 0, 0);
    }

    // bias + online softmax (rows 4*l4+r, 64 cols across 16 lanes x 4 frags)
    float pv[4][4];
#pragma unroll
    for (int r = 0; r < 4; ++r) {
      float svr[4], mx = -1e30f;
#pragma unroll
      for (int nf = 0; nf < 4; ++nf) {
        const float sv = sc[nf][r] * 0.125f +
                         brow[(long)(4 * l4 + r) * S + kv0 + nf * 16 + l15];
        svr[nf] = sv;
        mx = fmaxf(mx, sv);
      }
      mx = fmaxf(mx, __shfl_xor(mx, 1));
      mx = fmaxf(mx, __shfl_xor(mx, 2));
      mx = fmaxf(mx, __shfl_xor(mx, 4));
      mx = fmaxf(mx, __shfl_xor(mx, 8));
      const float mnew = fmaxf(mrun[r], mx);
      const float alpha = exp2f((mrun[r] - mnew) * LOG2E);
      mrun[r] = mnew;
      float rs = 0.f;
#pragma unroll
      for (int nf = 0; nf < 4; ++nf) {
        const float p = exp2f((svr[nf] - mnew) * LOG2E);
        pv[nf][r] = p;
        rs += p;
      }
      rs += __shfl_xor(rs, 1);
      rs += __shfl_xor(rs, 2);
      rs += __shfl_xor(rs, 4);
      rs += __shfl_xor(rs, 8);
      lsum[r] = lsum[r] * alpha + rs;
#pragma unroll
      for (int nf = 0; nf < 4; ++nf) oacc[nf][r] *= alpha;
    }

    // P -> LDS (per-wave buffer), then PV
#pragma unroll
    for (int nf = 0; nf < 4; ++nf)
#pragma unroll
      for (int r = 0; r < 4; ++r)
        p_sh[wave][(4 * l4 + r) * LKV + nf * 16 + l15] = f2bf(pv[nf][r]);
    __syncthreads();

    const bf16x8 pa0 = *reinterpret_cast<const bf16x8*>(&p_sh[wave][l15 * LKV + 8 * l4]);
    const bf16x8 pa1 = *reinterpret_cast<const bf16x8*>(&p_sh[wave][l15 * LKV + 8 * l4 + 32]);
#pragma unroll
    for (int nf = 0; nf < 4; ++nf) {
      const unsigned short* vr = &vt_sh[(nf * 16 + l15) * LKV + 8 * l4];
      const bf16x8 vf0 = *reinterpret_cast<const bf16x8*>(vr);
      const bf16x8 vf1 = *reinterpret_cast<const bf16x8*>(vr + 32);
      oacc[nf] = __builtin_amdgcn_mfma_f32_16x16x32_bf16(pa0, vf0, oacc[nf], 0, 0, 0);
      oacc[nf] = __builtin_amdgcn_mfma_f32_16x16x32_bf16(pa1, vf1, oacc[nf], 0, 0, 0);
    }
  }

  const int b = bh >> 4, h = bh & 15;
#pragma unroll
  for (int nf = 0; nf < 4; ++nf)
#pragma unroll
    for (int r = 0; r < 4; ++r) {
      const long s = q0 + wave * 16 + 4 * l4 + r;
      const long col = h * 64 + nf * 16 + l15;
      ctx[((long)b * S + s) * 1024 + col] = f2bf(oacc[nf][r] / lsum[r]);
    }
}

// ---------------------------------------------------------------------------
extern "C" void kernel_launch(void* const* d_in, const int* in_sizes, int n_in,
                              void* d_out, int out_size, void* d_ws, size_t ws_size,
                              hipStream_t stream) {
  const float* x    = (const float*)d_in[0];
  const float* ab   = (const float*)d_in[1];
  const float* ln1g = (const float*)d_in[2];
  const float* ln1b = (const float*)d_in[3];
  const float* Wqkv = (const float*)d_in[4];
  const float* bqkv = (const float*)d_in[5];
  const float* Wo   = (const float*)d_in[6];
  const float* bo   = (const float*)d_in[7];
  const float* ln2g = (const float*)d_in[8];
  const float* ln2b = (const float*)d_in[9];
  const float* W1   = (const float*)d_in[10];
  const float* b1   = (const float*)d_in[11];
  const float* W2   = (const float*)d_in[12];
  const float* b2   = (const float*)d_in[13];
  float* out = (float*)d_out;

  char* ws = (char*)d_ws;
  size_t off = 0;
  auto alloc = [&](size_t bytes) {
    char* p = ws + off;
    off += (bytes + 255) & ~(size_t)255;
    return p;
  };
  unsigned short* wqkv_t = (unsigned short*)alloc((size_t)3072 * 1024 * 2);
  unsigned short* wo_t   = (unsigned short*)alloc((size_t)1024 * 1024 * 2);
  unsigned short* w1_t   = (unsigned short*)alloc((size_t)4096 * 1024 * 2);
  unsigned short* w2_t   = (unsigned short*)alloc((size_t)4096 * 1024 * 2);
  unsigned short* h1     = (unsigned short*)alloc((size_t)2048 * 1024 * 2);  // ffn1 aliases h1..vtbuf
  unsigned short* qbuf   = (unsigned short*)alloc((size_t)2048 * 1024 * 2);
  unsigned short* kbuf   = (unsigned short*)alloc((size_t)2048 * 1024 * 2);
  unsigned short* vtbuf  = (unsigned short*)alloc((size_t)2048 * 1024 * 2);
  unsigned short* ctx    = (unsigned short*)alloc((size_t)2048 * 1024 * 2);
  unsigned short* h2     = (unsigned short*)alloc((size_t)2048 * 1024 * 2);
  float*          r1     = (float*)alloc((size_t)2048 * 1024 * 4);
  unsigned short* ffn1   = h1;  // 16MB alias over h1/qbuf/kbuf/vtbuf (dead after attn)
  (void)ws_size; (void)in_sizes; (void)n_in; (void)out_size;

  const dim3 tb(32, 8);
  convert_transpose<<<dim3(3072 / 32, 1024 / 32), tb, 0, stream>>>(Wqkv, wqkv_t, 1024, 3072);
  convert_transpose<<<dim3(1024 / 32, 1024 / 32), tb, 0, stream>>>(Wo, wo_t, 1024, 1024);
  convert_transpose<<<dim3(4096 / 32, 1024 / 32), tb, 0, stream>>>(W1, w1_t, 1024, 4096);
  convert_transpose<<<dim3(1024 / 32, 4096 / 32), tb, 0, stream>>>(W2, w2_t, 4096, 1024);

  ln_kernel<<<2048, 256, 0, stream>>>(x, ln1g, ln1b, h1);

  gemm_kernel<0><<<dim3(24, 16), 256, 0, stream>>>(h1, wqkv_t, bqkv, 2048, 3072, 1024,
                                                   nullptr, nullptr, qbuf, kbuf, vtbuf);

  attn_kernel<<<dim3(16, 32), 256, 0, stream>>>(qbuf, kbuf, vtbuf, ab, ctx);

  gemm_kernel<1><<<dim3(8, 16), 256, 0, stream>>>(ctx, wo_t, bo, 2048, 1024, 1024,
                                                  r1, x, nullptr, nullptr, nullptr);

  ln_kernel<<<2048, 256, 0, stream>>>(r1, ln2g, ln2b, h2);

  gemm_kernel<2><<<dim3(32, 16), 256, 0, stream>>>(h2, w1_t, b1, 2048, 4096, 1024,
                                                   nullptr, nullptr, ffn1, nullptr, nullptr);

  gemm_kernel<3><<<dim3(8, 16), 256, 0, stream>>>(ffn1, w2_t, b2, 2048, 1024, 4096,
                                                  out, r1, nullptr, nullptr, nullptr);
}

// Round 3
// 207.445 us; speedup vs baseline: 1.4329x; 1.4329x over previous
//
#include <hip/hip_runtime.h>

// ---------------------------------------------------------------------------
// TransformerBlock: LN1 -> QKV -> attn(+bias, softmax) -> Wo(+x) -> LN2
//                   -> FFN1(+mish) -> FFN2(+residual)
// fp32 I/O, bf16 MFMA GEMMs (16x16x32), flash-style attention.
// R3: global_load_lds staging (BK=64), XOR-swizzled LDS, XCD-aware x-major
//     block order, BN=64 tiles for the N=1024 GEMMs.
// ---------------------------------------------------------------------------

typedef __attribute__((ext_vector_type(8))) __bf16 bf16x8;
typedef __attribute__((ext_vector_type(4))) float  f32x4;

#define LOG2E 1.4426950408889634f

__device__ __forceinline__ unsigned short f2bf(float f) {
  unsigned int u = __builtin_bit_cast(unsigned int, f);
  u += 0x7fffu + ((u >> 16) & 1u);          // round-to-nearest-even
  return (unsigned short)(u >> 16);
}

__device__ __forceinline__ void gload16(const void* g, void* l) {
  __builtin_amdgcn_global_load_lds(
      (const __attribute__((address_space(1))) void*)g,
      (__attribute__((address_space(3))) void*)l, 16, 0, 0);
}

// ---------------------------------------------------------------------------
// Weight convert fp32 (K x N) -> bf16 transposed (N x K), LDS 32x33 tile.
// ---------------------------------------------------------------------------
__global__ void convert_transpose(const float* __restrict__ W,
                                  unsigned short* __restrict__ Wt,
                                  int K, int N) {
  __shared__ float tile[32][33];
  const int n0 = blockIdx.x * 32, k0 = blockIdx.y * 32;
  const int tx = threadIdx.x, ty = threadIdx.y;   // (32,8)
#pragma unroll
  for (int r = 0; r < 4; ++r)
    tile[ty + 8 * r][tx] = W[(size_t)(k0 + ty + 8 * r) * N + n0 + tx];
  __syncthreads();
#pragma unroll
  for (int r = 0; r < 4; ++r)
    Wt[(size_t)(n0 + ty + 8 * r) * K + k0 + tx] = f2bf(tile[tx][ty + 8 * r]);
}

// ---------------------------------------------------------------------------
// LayerNorm over D=1024, one row per block (256 threads, 4 f32/thread).
// ---------------------------------------------------------------------------
__global__ __launch_bounds__(256) void ln_kernel(const float* __restrict__ in,
                                                 const float* __restrict__ g,
                                                 const float* __restrict__ b,
                                                 unsigned short* __restrict__ out) {
  const int row = blockIdx.x;
  const int t = threadIdx.x;
  const float4 v = reinterpret_cast<const float4*>(in + (size_t)row * 1024)[t];
  float s  = v.x + v.y + v.z + v.w;
  float s2 = v.x * v.x + v.y * v.y + v.z * v.z + v.w * v.w;
#pragma unroll
  for (int m = 1; m < 64; m <<= 1) { s += __shfl_xor(s, m); s2 += __shfl_xor(s2, m); }
  __shared__ float ps[4], ps2[4];
  const int wv = t >> 6;
  if ((t & 63) == 0) { ps[wv] = s; ps2[wv] = s2; }
  __syncthreads();
  float ts = 0.f, ts2 = 0.f;
#pragma unroll
  for (int i = 0; i < 4; ++i) { ts += ps[i]; ts2 += ps2[i]; }
  const float mu = ts * (1.f / 1024.f);
  const float var = ts2 * (1.f / 1024.f) - mu * mu;
  const float rstd = rsqrtf(var + 1e-5f);
  const float4 gg = reinterpret_cast<const float4*>(g)[t];
  const float4 bb = reinterpret_cast<const float4*>(b)[t];
  ushort4 ov;
  ov.x = f2bf((v.x - mu) * rstd * gg.x + bb.x);
  ov.y = f2bf((v.y - mu) * rstd * gg.y + bb.y);
  ov.z = f2bf((v.z - mu) * rstd * gg.z + bb.z);
  ov.w = f2bf((v.w - mu) * rstd * gg.w + bb.w);
  *reinterpret_cast<ushort4*>(out + (size_t)row * 1024 + t * 4) = ov;
}

// ---------------------------------------------------------------------------
// GEMM: C(MxN) = A(MxK bf16 row-major) @ Bt(NxK bf16 row-major)^T + bias
// BM=128, BN in {64,128}, BK=64. global_load_lds staging, XOR-swizzled LDS
// (LDS[r][chunk j] = global[r][j ^ (r&7)], 16B chunks), XCD-chunked x-major
// block order.
// MODE 0: QKV scatter; MODE 1: r1=acc+bo+x (f32); MODE 2: mish (bf16);
// MODE 3: out=acc+b2+r1 (f32).
// ---------------------------------------------------------------------------
template <int MODE, int BN>
__global__ __launch_bounds__(256, 2) void gemm_kernel(
    const unsigned short* __restrict__ A, const unsigned short* __restrict__ Bt,
    const float* __restrict__ bias, int M, int N, int K,
    float* __restrict__ outf, const float* __restrict__ res,
    unsigned short* __restrict__ outb,
    unsigned short* __restrict__ kbuf, unsigned short* __restrict__ vtbuf) {
  constexpr int BM = 128, BK = 64;
  constexpr int WN = (BN == 128) ? 2 : 1;
  constexpr int WM = 4 / WN;
  constexpr int WR = BM / WM / 16;          // A-frags per wave
  constexpr int WC = BN / WN / 16;          // B-frags per wave
  __shared__ unsigned short a_sh[BM * BK];  // [row][64] linear
  __shared__ unsigned short b_sh[BN * BK];

  const int tid = threadIdx.x;
  const int wave = tid >> 6, lane = tid & 63;
  const int wm = wave / WN, wn = wave % WN;
  const int l15 = lane & 15, l4 = lane >> 4;

  // bijective XCD swizzle (gridDim.x % 8 == 0), then x-major decompose:
  // consecutive logical ids share the N-tile (B panel) within an XCD chunk.
  const int nwg = gridDim.x, cpx = nwg >> 3;
  const int swz = (blockIdx.x & 7) * cpx + (blockIdx.x >> 3);
  const int GY = M / BM;
  const long bm0 = (long)(swz % GY) * BM;
  const long bn0 = (long)(swz / GY) * BN;

  // staging geometry: 8 lanes per 128B row; source chunk inverse-swizzled.
  const int sr8 = lane >> 3;                // row within 8-row group
  const int gc  = ((lane & 7) ^ sr8) * 8;   // global chunk (shorts)

  const unsigned short* agp[BM / 32];
  const unsigned short* bgp[BN / 32];
  unsigned short* alb[BM / 32];
  unsigned short* blb[BN / 32];
#pragma unroll
  for (int i = 0; i < BM / 32; ++i) {
    const int r = wave * (BM / 4) + i * 8;  // wave-uniform base row
    agp[i] = A + (bm0 + r + sr8) * (long)K + gc;
    alb[i] = &a_sh[r * BK];
  }
#pragma unroll
  for (int i = 0; i < BN / 32; ++i) {
    const int r = wave * (BN / 4) + i * 8;
    bgp[i] = Bt + (bn0 + r + sr8) * (long)K + gc;
    blb[i] = &b_sh[r * BK];
  }

  f32x4 acc[WR][WC] = {};

  for (int k0 = 0; k0 < K; k0 += BK) {
    __syncthreads();                        // prev tile consumed
#pragma unroll
    for (int i = 0; i < BM / 32; ++i) gload16(agp[i] + k0, alb[i]);
#pragma unroll
    for (int i = 0; i < BN / 32; ++i) gload16(bgp[i] + k0, blb[i]);
    asm volatile("s_waitcnt vmcnt(0)" ::: "memory");
    __syncthreads();

#pragma unroll
    for (int kk = 0; kk < 2; ++kk) {
      bf16x8 af[WR], bfr[WC];
#pragma unroll
      for (int mf = 0; mf < WR; ++mf) {
        const int r = wm * (BM / WM) + mf * 16 + l15;
        const int c = ((kk * 4 + l4) ^ (r & 7)) * 8;
        af[mf] = *reinterpret_cast<const bf16x8*>(&a_sh[r * BK + c]);
      }
#pragma unroll
      for (int nf = 0; nf < WC; ++nf) {
        const int r = wn * (BN / WN) + nf * 16 + l15;
        const int c = ((kk * 4 + l4) ^ (r & 7)) * 8;
        bfr[nf] = *reinterpret_cast<const bf16x8*>(&b_sh[r * BK + c]);
      }
#pragma unroll
      for (int mf = 0; mf < WR; ++mf)
#pragma unroll
        for (int nf = 0; nf < WC; ++nf)
          acc[mf][nf] = __builtin_amdgcn_mfma_f32_16x16x32_bf16(af[mf], bfr[nf], acc[mf][nf], 0, 0, 0);
    }
  }

  // epilogue: C layout col = lane&15, row = 4*(lane>>4)+r
#pragma unroll
  for (int mf = 0; mf < WR; ++mf) {
#pragma unroll
    for (int nf = 0; nf < WC; ++nf) {
#pragma unroll
      for (int r = 0; r < 4; ++r) {
        const long row = bm0 + wm * (BM / WM) + mf * 16 + 4 * l4 + r;
        const long col = bn0 + wn * (BN / WN) + nf * 16 + l15;
        float v = acc[mf][nf][r] + bias[col];
        if constexpr (MODE == 0) {
          const int n = (int)col;
          const int which = n >> 10, rem = n & 1023;
          const int head = rem >> 6, d = rem & 63;
          const int b = (int)(row >> 10), s = (int)(row & 1023);
          const unsigned short bv = f2bf(v);
          const long qi = ((long)(b * 16 + head) * 1024 + s) * 64 + d;
          if (which == 0)      outb[qi] = bv;
          else if (which == 1) kbuf[qi] = bv;
          else                 vtbuf[((long)(b * 16 + head) * 64 + d) * 1024 + s] = bv;
        } else if constexpr (MODE == 1) {
          outf[row * N + col] = v + res[row * N + col];
        } else if constexpr (MODE == 2) {
          // mish(v) = v * (t^2+2t)/(t^2+2t+2), t = e^v  (guard overflow)
          float mv;
          if (v > 20.f) mv = v;
          else { const float t = __expf(v); const float u = t * t + 2.f * t;
                 mv = v * u / (u + 2.f); }
          outb[row * (long)N + col] = f2bf(mv);
        } else {
          outf[row * N + col] = v + res[row * N + col];
        }
      }
    }
  }
}

// ---------------------------------------------------------------------------
// Flash attention: grid (S/64, B*H), 256 threads (4 waves x 16 q-rows).
// K staged [kv][d], V staged pre-transposed [d][kv]; online softmax; P via LDS.
// ---------------------------------------------------------------------------
__global__ __launch_bounds__(256, 2) void attn_kernel(
    const unsigned short* __restrict__ qb, const unsigned short* __restrict__ kb,
    const unsigned short* __restrict__ vtb, const float* __restrict__ bias,
    unsigned short* __restrict__ ctx) {
  constexpr int S = 1024, LKV = 72;
  __shared__ unsigned short k_sh[64 * LKV];
  __shared__ unsigned short vt_sh[64 * LKV];
  __shared__ unsigned short p_sh[4][16 * LKV];

  const int bh = blockIdx.y;
  const int q0 = blockIdx.x * 64;
  const int tid = threadIdx.x, wave = tid >> 6, lane = tid & 63;
  const int l15 = lane & 15, l4 = lane >> 4;

  const long qbase = ((long)bh * S + q0 + wave * 16 + l15) * 64;
  const bf16x8 qf0 = *reinterpret_cast<const bf16x8*>(qb + qbase + 8 * l4);
  const bf16x8 qf1 = *reinterpret_cast<const bf16x8*>(qb + qbase + 8 * l4 + 32);

  const int srow = tid >> 2;              // 0..63
  const int scol = (tid & 3) * 16;

  f32x4 oacc[4] = {};
  float mrun[4], lsum[4] = {};
#pragma unroll
  for (int r = 0; r < 4; ++r) mrun[r] = -1e30f;

  const float* brow = bias + ((long)bh * S + q0 + wave * 16) * S;

  for (int kv0 = 0; kv0 < S; kv0 += 64) {
    const unsigned short* kG = kb + ((long)bh * S + kv0 + srow) * 64 + scol;
    const unsigned short* vG = vtb + ((long)bh * 64 + srow) * S + kv0 + scol;
    const uint4 k0v = reinterpret_cast<const uint4*>(kG)[0];
    const uint4 k1v = reinterpret_cast<const uint4*>(kG)[1];
    const uint4 v0v = reinterpret_cast<const uint4*>(vG)[0];
    const uint4 v1v = reinterpret_cast<const uint4*>(vG)[1];
    __syncthreads();
    reinterpret_cast<uint4*>(&k_sh[srow * LKV + scol])[0] = k0v;
    reinterpret_cast<uint4*>(&k_sh[srow * LKV + scol + 8])[0] = k1v;
    reinterpret_cast<uint4*>(&vt_sh[srow * LKV + scol])[0] = v0v;
    reinterpret_cast<uint4*>(&vt_sh[srow * LKV + scol + 8])[0] = v1v;
    __syncthreads();

    f32x4 sc[4];
#pragma unroll
    for (int nf = 0; nf < 4; ++nf) {
      const unsigned short* kr = &k_sh[(nf * 16 + l15) * LKV + 8 * l4];
      const bf16x8 kf0 = *reinterpret_cast<const bf16x8*>(kr);
      const bf16x8 kf1 = *reinterpret_cast<const bf16x8*>(kr + 32);
      f32x4 z = {};
      z = __builtin_amdgcn_mfma_f32_16x16x32_bf16(qf0, kf0, z, 0, 0, 0);
      sc[nf] = __builtin_amdgcn_mfma_f32_16x16x32_bf16(qf1, kf1, z, 0, 0, 0);
    }

    float pv[4][4];
#pragma unroll
    for (int r = 0; r < 4; ++r) {
      float svr[4], mx = -1e30f;
#pragma unroll
      for (int nf = 0; nf < 4; ++nf) {
        const float sv = sc[nf][r] * 0.125f +
                         brow[(long)(4 * l4 + r) * S + kv0 + nf * 16 + l15];
        svr[nf] = sv;
        mx = fmaxf(mx, sv);
      }
      mx = fmaxf(mx, __shfl_xor(mx, 1));
      mx = fmaxf(mx, __shfl_xor(mx, 2));
      mx = fmaxf(mx, __shfl_xor(mx, 4));
      mx = fmaxf(mx, __shfl_xor(mx, 8));
      const float mnew = fmaxf(mrun[r], mx);
      const float alpha = exp2f((mrun[r] - mnew) * LOG2E);
      mrun[r] = mnew;
      float rs = 0.f;
#pragma unroll
      for (int nf = 0; nf < 4; ++nf) {
        const float p = exp2f((svr[nf] - mnew) * LOG2E);
        pv[nf][r] = p;
        rs += p;
      }
      rs += __shfl_xor(rs, 1);
      rs += __shfl_xor(rs, 2);
      rs += __shfl_xor(rs, 4);
      rs += __shfl_xor(rs, 8);
      lsum[r] = lsum[r] * alpha + rs;
#pragma unroll
      for (int nf = 0; nf < 4; ++nf) oacc[nf][r] *= alpha;
    }

#pragma unroll
    for (int nf = 0; nf < 4; ++nf)
#pragma unroll
      for (int r = 0; r < 4; ++r)
        p_sh[wave][(4 * l4 + r) * LKV + nf * 16 + l15] = f2bf(pv[nf][r]);
    __syncthreads();

    const bf16x8 pa0 = *reinterpret_cast<const bf16x8*>(&p_sh[wave][l15 * LKV + 8 * l4]);
    const bf16x8 pa1 = *reinterpret_cast<const bf16x8*>(&p_sh[wave][l15 * LKV + 8 * l4 + 32]);
#pragma unroll
    for (int nf = 0; nf < 4; ++nf) {
      const unsigned short* vr = &vt_sh[(nf * 16 + l15) * LKV + 8 * l4];
      const bf16x8 vf0 = *reinterpret_cast<const bf16x8*>(vr);
      const bf16x8 vf1 = *reinterpret_cast<const bf16x8*>(vr + 32);
      oacc[nf] = __builtin_amdgcn_mfma_f32_16x16x32_bf16(pa0, vf0, oacc[nf], 0, 0, 0);
      oacc[nf] = __builtin_amdgcn_mfma_f32_16x16x32_bf16(pa1, vf1, oacc[nf], 0, 0, 0);
    }
  }

  const int b = bh >> 4, h = bh & 15;
#pragma unroll
  for (int nf = 0; nf < 4; ++nf)
#pragma unroll
    for (int r = 0; r < 4; ++r) {
      const long s = q0 + wave * 16 + 4 * l4 + r;
      const long col = h * 64 + nf * 16 + l15;
      ctx[((long)b * S + s) * 1024 + col] = f2bf(oacc[nf][r] / lsum[r]);
    }
}

// ---------------------------------------------------------------------------
extern "C" void kernel_launch(void* const* d_in, const int* in_sizes, int n_in,
                              void* d_out, int out_size, void* d_ws, size_t ws_size,
                              hipStream_t stream) {
  const float* x    = (const float*)d_in[0];
  const float* ab   = (const float*)d_in[1];
  const float* ln1g = (const float*)d_in[2];
  const float* ln1b = (const float*)d_in[3];
  const float* Wqkv = (const float*)d_in[4];
  const float* bqkv = (const float*)d_in[5];
  const float* Wo   = (const float*)d_in[6];
  const float* bo   = (const float*)d_in[7];
  const float* ln2g = (const float*)d_in[8];
  const float* ln2b = (const float*)d_in[9];
  const float* W1   = (const float*)d_in[10];
  const float* b1   = (const float*)d_in[11];
  const float* W2   = (const float*)d_in[12];
  const float* b2   = (const float*)d_in[13];
  float* out = (float*)d_out;

  char* ws = (char*)d_ws;
  size_t off = 0;
  auto alloc = [&](size_t bytes) {
    char* p = ws + off;
    off += (bytes + 255) & ~(size_t)255;
    return p;
  };
  unsigned short* wqkv_t = (unsigned short*)alloc((size_t)3072 * 1024 * 2);
  unsigned short* wo_t   = (unsigned short*)alloc((size_t)1024 * 1024 * 2);
  unsigned short* w1_t   = (unsigned short*)alloc((size_t)4096 * 1024 * 2);
  unsigned short* w2_t   = (unsigned short*)alloc((size_t)4096 * 1024 * 2);
  unsigned short* h1     = (unsigned short*)alloc((size_t)2048 * 1024 * 2);  // ffn1 aliases h1..vtbuf
  unsigned short* qbuf   = (unsigned short*)alloc((size_t)2048 * 1024 * 2);
  unsigned short* kbuf   = (unsigned short*)alloc((size_t)2048 * 1024 * 2);
  unsigned short* vtbuf  = (unsigned short*)alloc((size_t)2048 * 1024 * 2);
  unsigned short* ctx    = (unsigned short*)alloc((size_t)2048 * 1024 * 2);
  unsigned short* h2     = (unsigned short*)alloc((size_t)2048 * 1024 * 2);
  float*          r1     = (float*)alloc((size_t)2048 * 1024 * 4);
  unsigned short* ffn1   = h1;  // 16MB alias over h1/qbuf/kbuf/vtbuf (dead after attn)
  (void)ws_size; (void)in_sizes; (void)n_in; (void)out_size;

  const dim3 tb(32, 8);
  convert_transpose<<<dim3(3072 / 32, 1024 / 32), tb, 0, stream>>>(Wqkv, wqkv_t, 1024, 3072);
  convert_transpose<<<dim3(1024 / 32, 1024 / 32), tb, 0, stream>>>(Wo, wo_t, 1024, 1024);
  convert_transpose<<<dim3(4096 / 32, 1024 / 32), tb, 0, stream>>>(W1, w1_t, 1024, 4096);
  convert_transpose<<<dim3(1024 / 32, 4096 / 32), tb, 0, stream>>>(W2, w2_t, 4096, 1024);

  ln_kernel<<<2048, 256, 0, stream>>>(x, ln1g, ln1b, h1);

  gemm_kernel<0, 128><<<384, 256, 0, stream>>>(h1, wqkv_t, bqkv, 2048, 3072, 1024,
                                               nullptr, nullptr, qbuf, kbuf, vtbuf);

  attn_kernel<<<dim3(16, 32), 256, 0, stream>>>(qbuf, kbuf, vtbuf, ab, ctx);

  gemm_kernel<1, 64><<<256, 256, 0, stream>>>(ctx, wo_t, bo, 2048, 1024, 1024,
                                              r1, x, nullptr, nullptr, nullptr);

  ln_kernel<<<2048, 256, 0, stream>>>(r1, ln2g, ln2b, h2);

  gemm_kernel<2, 128><<<512, 256, 0, stream>>>(h2, w1_t, b1, 2048, 4096, 1024,
                                               nullptr, nullptr, ffn1, nullptr, nullptr);

  gemm_kernel<3, 64><<<256, 256, 0, stream>>>(ffn1, w2_t, b2, 2048, 1024, 4096,
                                              out, r1, nullptr, nullptr, nullptr);
}